// Round 6
// baseline (531.889 us; speedup 1.0000x reference)
//
#include <hip/hip_runtime.h>

// Side Window Filter — bit-exact vs harness np ref (absmax 0.0 contract).
// Math contract (DO NOT REORDER): per output, each of the 8 windows is a
// sequential __builtin_fmaf chain over its taps in row-major (i,j) order,
// fp32 accumulator starting at 0, weights fp32(1/15), fp32(1/9); replicate
// boundary; 8 iterations; fp32 iterates; fp32 d/argmin(first-idx)/update;
// final clip(|x0-res|,0,255).
//
// R16 = R15 (pair-processing, flat global loads, no LDS/barrier) with the
// two spill drivers fixed:
//  1. Register pinning via the PURE attribute form
//     amdgpu_flat_work_group_size(256,256) + amdgpu_waves_per_eu(2,3).
//     R15's launch_bounds+waves_per_eu combo was ignored (VGPR 84, ~50 MB
//     scratch traffic/dispatch): allocator targeted 6 waves/EU and
//     spilled. Cap occupancy at 3 waves/EU -> ~170 VGPR budget for the
//     ~110 live floats.
//  2. Unified edge path: instead of a persistent cjk[4][5] index array
//     (20 ints live across the whole i-loop, unioned with the fast
//     path's registers), build the same r[20] window per row with 20
//     pixel-clamped scalar loads: float x of the window is unclamped
//     index f = col4-8+x; f<0 -> ((f%3)+3)%3, f>=WC -> (W-1)*3+f%3
//     (channel-preserving pixel replicate — same verified identity as
//     the R12/R13 LDS halo). Both paths then share apply_phase_r.
//
// Pair dataflow: each thread owns 4 columns x output rows (2y, 2y+1).
// Walk the 6-row window union once; row i feeds phase i of row A (i<=4)
// and phase i-1 of row B (i>=1) from the same 5 float4 loads. Each acc
// chain still sees its taps in exact row-major order -> bit-exact
// (independent fp32 chains, interleaved but never reordered).

static constexpr int H  = 2048;
static constexpr int W  = 2048;
static constexpr int C  = 3;
static constexpr int WC = W * C;   // 6144 floats per row

// One window-row phase of the 8 directional chains for one output column.
// ph/k are compile-time at every call site (unrolled loops) so branches
// fold. Chain statement order is IDENTICAL to the verified R10/R13 kernels.
__device__ __forceinline__ void apply_phase_r(float* __restrict__ a,
                                              const float* __restrict__ r,
                                              int k, int ph, float& center,
                                              float w15, float w9) {
  const float t0 = r[k+2], t1 = r[k+5], t2 = r[k+8],
              t3 = r[k+11], t4 = r[k+14];
  if (ph == 2) center = t2;
  // L: cols 0..2, all rows
  a[0]=__builtin_fmaf(w15,t0,a[0]); a[0]=__builtin_fmaf(w15,t1,a[0]); a[0]=__builtin_fmaf(w15,t2,a[0]);
  // R: cols 2..4, all rows
  a[1]=__builtin_fmaf(w15,t2,a[1]); a[1]=__builtin_fmaf(w15,t3,a[1]); a[1]=__builtin_fmaf(w15,t4,a[1]);
  if (ph <= 2) {  // U: rows 0..2, all cols
    a[2]=__builtin_fmaf(w15,t0,a[2]); a[2]=__builtin_fmaf(w15,t1,a[2]); a[2]=__builtin_fmaf(w15,t2,a[2]);
    a[2]=__builtin_fmaf(w15,t3,a[2]); a[2]=__builtin_fmaf(w15,t4,a[2]);
    // NW / NE
    a[4]=__builtin_fmaf(w9,t0,a[4]); a[4]=__builtin_fmaf(w9,t1,a[4]); a[4]=__builtin_fmaf(w9,t2,a[4]);
    a[5]=__builtin_fmaf(w9,t2,a[5]); a[5]=__builtin_fmaf(w9,t3,a[5]); a[5]=__builtin_fmaf(w9,t4,a[5]);
  }
  if (ph >= 2) {  // D: rows 2..4, all cols
    a[3]=__builtin_fmaf(w15,t0,a[3]); a[3]=__builtin_fmaf(w15,t1,a[3]); a[3]=__builtin_fmaf(w15,t2,a[3]);
    a[3]=__builtin_fmaf(w15,t3,a[3]); a[3]=__builtin_fmaf(w15,t4,a[3]);
    // SW / SE
    a[6]=__builtin_fmaf(w9,t0,a[6]); a[6]=__builtin_fmaf(w9,t1,a[6]); a[6]=__builtin_fmaf(w9,t2,a[6]);
    a[7]=__builtin_fmaf(w9,t2,a[7]); a[7]=__builtin_fmaf(w9,t3,a[7]); a[7]=__builtin_fmaf(w9,t4,a[7]);
  }
}

// fp32 d/argmin/update epilogue for one output column (order-contractual).
__device__ __forceinline__ float finish(const float* __restrict__ a,
                                        float center) {
  float best  = a[0] - center;
  float besta = fabsf(best);
#pragma unroll
  for (int m = 1; m < 8; ++m) {
    const float d  = a[m] - center;
    const float ab = fabsf(d);
    if (ab < besta) { besta = ab; best = d; }
  }
  return center + best;
}

template<bool FINAL>
__global__
__attribute__((amdgpu_flat_work_group_size(256, 256), amdgpu_waves_per_eu(2, 3)))
void swf_pg(const float* __restrict__ src, float* __restrict__ dst,
            const float* __restrict__ x0) {
  const int col4 = (blockIdx.x * 256 + threadIdx.x) * 4;  // 16B-aligned
  const int yA   = blockIdx.y * 2;                        // rows yA, yA+1

  const float w15 = 1.0f / 15.0f;   // fp32(1/15)
  const float w9  = 1.0f / 9.0f;    // fp32(1/9)

  float accA[4][8], accB[4][8];
#pragma unroll
  for (int k = 0; k < 4; ++k)
#pragma unroll
    for (int m = 0; m < 8; ++m) { accA[k][m] = 0.0f; accB[k][m] = 0.0f; }
  float centerA[4], centerB[4];

  // fast iff all taps for cols col4..col4+3 lie in [col4-8, col4+12)
  const bool fastc = (col4 >= 8) && (col4 <= WC - 12);
  if (fastc) {
    const float* colbase = src + (col4 - 8);
    // walk the 6-row union: row yA+i-2 feeds phase i of A (i<=4) and
    // phase i-1 of B (i>=1)
#pragma unroll
    for (int i = 0; i < 6; ++i) {
      int hy = yA + i - 2;
      hy = hy < 0 ? 0 : (hy > H - 1 ? H - 1 : hy);     // replicate rows
      const float4* rp = (const float4*)(colbase + (size_t)hy * WC);
      const float4 q0 = rp[0], q1 = rp[1], q2 = rp[2], q3 = rp[3], q4 = rp[4];
      const float r[20] = {q0.x,q0.y,q0.z,q0.w, q1.x,q1.y,q1.z,q1.w,
                           q2.x,q2.y,q2.z,q2.w, q3.x,q3.y,q3.z,q3.w,
                           q4.x,q4.y,q4.z,q4.w};
#pragma unroll
      for (int k = 0; k < 4; ++k) {
        if (i <= 4) apply_phase_r(accA[k], r, k, i,     centerA[k], w15, w9);
        if (i >= 1) apply_phase_r(accB[k], r, k, i - 1, centerB[k], w15, w9);
      }
    }
  } else {
    // edge columns (col4 in {0,4,WC-8,WC-4}): build the same 20-float
    // window per row via pixel-clamped scalar loads (halo identity:
    // float x <-> unclamped idx f = col4-8+x; channel preserved).
    const int base = col4 - 8;
#pragma unroll
    for (int i = 0; i < 6; ++i) {
      int hy = yA + i - 2;
      hy = hy < 0 ? 0 : (hy > H - 1 ? H - 1 : hy);
      const float* rr = src + (size_t)hy * WC;
      float r[20];
#pragma unroll
      for (int x = 0; x < 20; ++x) {
        const int f = base + x;
        const int idx = (f < 0)    ? ((f % 3) + 3) % 3
                      : (f >= WC)  ? (W - 1) * 3 + (f % 3)
                      : f;
        r[x] = rr[idx];
      }
#pragma unroll
      for (int k = 0; k < 4; ++k) {
        if (i <= 4) apply_phase_r(accA[k], r, k, i,     centerA[k], w15, w9);
        if (i >= 1) apply_phase_r(accB[k], r, k, i - 1, centerB[k], w15, w9);
      }
    }
  }

  // epilogue: two output rows, fp32 d/argmin/update, float4 stores
#pragma unroll
  for (int half = 0; half < 2; ++half) {
    const int y = yA + half;
    float4 xv4;
    if (FINAL) xv4 = *(const float4*)(x0 + (size_t)y * WC + col4);
    float o[4];
#pragma unroll
    for (int k = 0; k < 4; ++k) {
      const float res = half ? finish(accB[k], centerB[k])
                             : finish(accA[k], centerA[k]);
      if (FINAL) {
        const float xv = (k == 0) ? xv4.x : (k == 1) ? xv4.y
                       : (k == 2) ? xv4.z : xv4.w;
        float diff = fabsf(xv - res);
        o[k] = diff > 255.0f ? 255.0f : diff;
      } else {
        o[k] = res;
      }
    }
    float4 ov;
    ov.x = o[0]; ov.y = o[1]; ov.z = o[2]; ov.w = o[3];
    *(float4*)(dst + (size_t)y * WC + col4) = ov;
  }
}

extern "C" void kernel_launch(void* const* d_in, const int* in_sizes, int n_in,
                              void* d_out, int out_size, void* d_ws, size_t ws_size,
                              hipStream_t stream) {
  const float* x0  = (const float*)d_in[0];
  float*       out = (float*)d_out;
  float*       ws  = (float*)d_ws;   // needs H*W*C*4 = 50.3 MB

  dim3 grid(WC / 1024, H / 2);       // 6 x-blocks (256 thr x 4 cols), 1024 row-pairs
  dim3 block(256);

  swf_pg<false><<<grid, block, 0, stream>>>(x0,  ws,  nullptr);  // iter 1
  swf_pg<false><<<grid, block, 0, stream>>>(ws,  out, nullptr);  // iter 2
  swf_pg<false><<<grid, block, 0, stream>>>(out, ws,  nullptr);  // iter 3
  swf_pg<false><<<grid, block, 0, stream>>>(ws,  out, nullptr);  // iter 4
  swf_pg<false><<<grid, block, 0, stream>>>(out, ws,  nullptr);  // iter 5
  swf_pg<false><<<grid, block, 0, stream>>>(ws,  out, nullptr);  // iter 6
  swf_pg<false><<<grid, block, 0, stream>>>(out, ws,  nullptr);  // iter 7
  swf_pg<true ><<<grid, block, 0, stream>>>(ws,  out, x0);       // iter 8 + diff
}